// Round 1
// baseline (208.465 us; speedup 1.0000x reference)
//
#include <hip/hip_runtime.h>
#include <math.h>

#define BB 64
#define SS 2048
#define HH 1024
#define NCHUNK 16
#define CHUNK 128  // SS / NCHUNK

// ws layout (floats):
//   q:         [B][H]           offset 0
//   part_ctx:  [B][NCHUNK][H]   offset 65536
//   part_ml:   [B][NCHUNK][2]   offset 65536 + B*NCHUNK*H
//   ctx_final: [B][H]
#define Q_OFF    0
#define PCTX_OFF (BB * HH)
#define PML_OFF  (PCTX_OFF + BB * NCHUNK * HH)
#define CTXF_OFF (PML_OFF + BB * NCHUNK * 2)
// total = CTXF_OFF + BB*HH = 1,181,696 floats = ~4.73 MB

// ---------------------------------------------------------------------------
// Generic tiny GEMM: out[b][i] = act( sum_j A(b,j) * W[i*K + j] ), b<64, i<1024
// A(b,j) = j < 1024 ? A0[b*1024+j] : A1[b*1024 + (j-1024)]
// grid.x = 256 (i-tiles of 4), 256 threads. K = nchunks*256.
// ---------------------------------------------------------------------------
__global__ __launch_bounds__(256) void gemm64(
    const float* __restrict__ A0, const float* __restrict__ A1,
    const float* __restrict__ W, float* __restrict__ out,
    int nchunks, int do_tanh)
{
    __shared__ float A_lds[64 * 256];  // xor-swizzled float4 granules
    __shared__ float W_lds[4 * 256];
    const int t  = threadIdx.x;
    const int it = blockIdx.x;
    const int b  = t & 63;
    const int il = t >> 6;
    const int K  = nchunks << 8;
    float acc = 0.f;

    for (int kc = 0; kc < nchunks; ++kc) {
        // stage A chunk [64][256] with per-row XOR swizzle of float4 granules
        for (int idx = t; idx < 64 * 64; idx += 256) {
            const int row = idx >> 6;
            const int g   = idx & 63;
            const float* src = (kc < 4) ? (A0 + row * 1024 + kc * 256)
                                        : (A1 + row * 1024 + (kc - 4) * 256);
            float4 v = *(const float4*)(src + g * 4);
            ((float4*)A_lds)[row * 64 + (g ^ row)] = v;
        }
        // stage W chunk [4][256]
        for (int idx = t; idx < 1024; idx += 256) {
            const int r2 = idx >> 8;
            const int cc = idx & 255;
            W_lds[idx] = W[(size_t)(it * 4 + r2) * K + kc * 256 + cc];
        }
        __syncthreads();
        #pragma unroll 8
        for (int j4 = 0; j4 < 64; ++j4) {
            float4 a  = ((const float4*)A_lds)[b * 64 + (j4 ^ b)];
            float4 wv = ((const float4*)W_lds)[il * 64 + j4];
            acc += a.x * wv.x + a.y * wv.y + a.z * wv.z + a.w * wv.w;
        }
        __syncthreads();
    }
    if (do_tanh) acc = tanhf(acc);
    out[b * 1024 + it * 4 + il] = acc;
}

// ---------------------------------------------------------------------------
// Main one-pass kernel: per (chunk, b) block computes raw scores + online
// softmax partial context. enc row stays in registers between score and
// accumulate (single HBM read of enc_outs).
// grid = (NCHUNK, B), 256 threads (4 waves), each wave owns CHUNK/4 s-rows.
// ---------------------------------------------------------------------------
__global__ __launch_bounds__(256) void attn_partial(
    const float* __restrict__ enc, const float* __restrict__ q,
    float* __restrict__ part_ctx, float* __restrict__ part_ml,
    float* __restrict__ scores_raw)
{
    __shared__ float q_lds[HH];
    __shared__ float ctx_lds[4][HH];
    __shared__ float ml_lds[4][2];

    const int t = threadIdx.x;
    const int c = blockIdx.x;
    const int b = blockIdx.y;

    for (int i = t; i < HH / 4; i += 256)
        ((float4*)q_lds)[i] = ((const float4*)(q + b * HH))[i];
    __syncthreads();

    const int w    = t >> 6;
    const int lane = t & 63;
    float m = -INFINITY, lsum = 0.f;
    float ctx[16];
    #pragma unroll
    for (int e = 0; e < 16; ++e) ctx[e] = 0.f;

    const int RPW = CHUNK / 4;  // rows per wave
    for (int r = 0; r < RPW; ++r) {
        const int s = c * CHUNK + w * RPW + r;
        const float* row = enc + ((size_t)s * BB + b) * HH;
        float4 v[4];
        float partial = 0.f;
        #pragma unroll
        for (int k = 0; k < 4; ++k) {
            v[k] = *(const float4*)(row + k * 256 + 4 * lane);
            float4 qv = *(const float4*)(q_lds + k * 256 + 4 * lane);
            partial += v[k].x * qv.x + v[k].y * qv.y + v[k].z * qv.z + v[k].w * qv.w;
        }
        #pragma unroll
        for (int off = 32; off; off >>= 1)
            partial += __shfl_xor(partial, off, 64);
        const float sc = partial;  // uniform across wave
        if (lane == 0) scores_raw[b * SS + s] = sc;

        if (sc > m) {  // wave-uniform branch
            const float scale = expf(m - sc);  // expf(-inf)=0 on first row
            lsum *= scale;
            #pragma unroll
            for (int e = 0; e < 16; ++e) ctx[e] *= scale;
            m = sc;
        }
        const float p = expf(sc - m);
        lsum += p;
        #pragma unroll
        for (int k = 0; k < 4; ++k) {
            ctx[4 * k + 0] += p * v[k].x;
            ctx[4 * k + 1] += p * v[k].y;
            ctx[4 * k + 2] += p * v[k].z;
            ctx[4 * k + 3] += p * v[k].w;
        }
    }

    if (lane == 0) { ml_lds[w][0] = m; ml_lds[w][1] = lsum; }
    #pragma unroll
    for (int k = 0; k < 4; ++k)
        *(float4*)&ctx_lds[w][k * 256 + 4 * lane] =
            make_float4(ctx[4 * k + 0], ctx[4 * k + 1], ctx[4 * k + 2], ctx[4 * k + 3]);
    __syncthreads();

    const float m0 = ml_lds[0][0], m1 = ml_lds[1][0], m2 = ml_lds[2][0], m3 = ml_lds[3][0];
    const float mb = fmaxf(fmaxf(m0, m1), fmaxf(m2, m3));
    const float f0 = expf(m0 - mb), f1 = expf(m1 - mb), f2 = expf(m2 - mb), f3 = expf(m3 - mb);
    const float lb = f0 * ml_lds[0][1] + f1 * ml_lds[1][1] + f2 * ml_lds[2][1] + f3 * ml_lds[3][1];

    float4 a0 = ((const float4*)&ctx_lds[0][0])[t];
    float4 a1 = ((const float4*)&ctx_lds[1][0])[t];
    float4 a2 = ((const float4*)&ctx_lds[2][0])[t];
    float4 a3 = ((const float4*)&ctx_lds[3][0])[t];
    float4 o;
    o.x = f0 * a0.x + f1 * a1.x + f2 * a2.x + f3 * a3.x;
    o.y = f0 * a0.y + f1 * a1.y + f2 * a2.y + f3 * a3.y;
    o.z = f0 * a0.z + f1 * a1.z + f2 * a2.z + f3 * a3.z;
    o.w = f0 * a0.w + f1 * a1.w + f2 * a2.w + f3 * a3.w;
    ((float4*)(part_ctx + ((size_t)b * NCHUNK + c) * HH))[t] = o;
    if (t == 0) {
        part_ml[(b * NCHUNK + c) * 2 + 0] = mb;
        part_ml[(b * NCHUNK + c) * 2 + 1] = lb;
    }
}

// ---------------------------------------------------------------------------
// Per-b combine of NCHUNK partials -> ctx_final; normalize weights in place.
// grid = B, 256 threads.
// ---------------------------------------------------------------------------
__global__ __launch_bounds__(256) void attn_combine(
    const float* __restrict__ part_ctx, const float* __restrict__ part_ml,
    float* __restrict__ ctx_final, float* __restrict__ wts)
{
    const int b = blockIdx.x;
    const int t = threadIdx.x;
    __shared__ float mls[NCHUNK][2];
    for (int i = t; i < NCHUNK * 2; i += 256)
        ((float*)mls)[i] = part_ml[b * NCHUNK * 2 + i];
    __syncthreads();

    float M = -INFINITY;
    #pragma unroll
    for (int c2 = 0; c2 < NCHUNK; ++c2) M = fmaxf(M, mls[c2][0]);
    float f[NCHUNK];
    float L = 0.f;
    #pragma unroll
    for (int c2 = 0; c2 < NCHUNK; ++c2) {
        f[c2] = expf(mls[c2][0] - M);
        L += f[c2] * mls[c2][1];
    }
    const float inv = 1.0f / L;

    float4 acc = make_float4(0.f, 0.f, 0.f, 0.f);
    #pragma unroll
    for (int c2 = 0; c2 < NCHUNK; ++c2) {
        float4 v = ((const float4*)(part_ctx + ((size_t)b * NCHUNK + c2) * HH))[t];
        acc.x += f[c2] * v.x; acc.y += f[c2] * v.y;
        acc.z += f[c2] * v.z; acc.w += f[c2] * v.w;
    }
    acc.x *= inv; acc.y *= inv; acc.z *= inv; acc.w *= inv;
    ((float4*)(ctx_final + (size_t)b * HH))[t] = acc;

    for (int s = t; s < SS; s += 256)
        wts[b * SS + s] = expf(wts[b * SS + s] - M) * inv;
}

extern "C" void kernel_launch(void* const* d_in, const int* in_sizes, int n_in,
                              void* d_out, int out_size, void* d_ws, size_t ws_size,
                              hipStream_t stream)
{
    const float* dec   = (const float*)d_in[0];  // [B,H]
    const float* enc   = (const float*)d_in[1];  // [S,B,H]
    const float* W_a   = (const float*)d_in[2];  // [H,H]
    const float* W_out = (const float*)d_in[3];  // [H,2H]
    float* out = (float*)d_out;                  // [B*H] context, then [B*S] weights
    float* ws  = (float*)d_ws;

    float* q         = ws + Q_OFF;
    float* part_ctx  = ws + PCTX_OFF;
    float* part_ml   = ws + PML_OFF;
    float* ctx_final = ws + CTXF_OFF;
    float* wts       = out + BB * HH;  // weights region of d_out

    // 1) q = dec @ W_a^T
    gemm64<<<256, 256, 0, stream>>>(dec, dec, W_a, q, 4, 0);
    // 2) one-pass scores + online-softmax partial context
    attn_partial<<<dim3(NCHUNK, BB), 256, 0, stream>>>(enc, q, part_ctx, part_ml, wts);
    // 3) combine partials, normalize weights in place
    attn_combine<<<BB, 256, 0, stream>>>(part_ctx, part_ml, ctx_final, wts);
    // 4) out = tanh(concat(ctx, dec) @ W_out^T)
    gemm64<<<256, 256, 0, stream>>>(ctx_final, dec, W_out, out, 8, 1);
}